// Round 2
// baseline (2588.032 us; speedup 1.0000x reference)
//
#include <hip/hip_runtime.h>
#include <hip/hip_bf16.h>

#define PI_F 3.14159265358979323846f

static inline size_t align256(size_t x) { return (x + 255) & ~size_t(255); }

// ---------------- bucketing (replaces CSR build) ----------------
// Buckets of 64 consecutive dst nodes. Edge packed as (local_dst<<17)|src
// (src < 2^17 since N=100000; local_dst < 64).

__global__ void bucket_fill_kernel(const int* __restrict__ src, const int* __restrict__ dst,
                                   int* __restrict__ bkt_cnt, unsigned* __restrict__ bkt_data,
                                   int E, int CAP) {
    int e = blockIdx.x * 256 + threadIdx.x;
    if (e >= E) return;
    int d = dst[e];
    int b = d >> 6;
    int p = atomicAdd(&bkt_cnt[b], 1);
    if (p < CAP) bkt_data[(size_t)b * CAP + p] = ((unsigned)(d & 63) << 17) | (unsigned)src[e];
}

// per-bucket degree histogram -> dinv = rsqrt(deg+1)  (self-loop included)
__global__ void deg_kernel(const int* __restrict__ bkt_cnt, const unsigned* __restrict__ bkt_data,
                           float* __restrict__ dinv, int N, int CAP) {
    __shared__ int hist[64];
    int b = blockIdx.x;
    if (threadIdx.x < 64) hist[threadIdx.x] = 0;
    __syncthreads();
    int cnt = min(bkt_cnt[b], CAP);
    const unsigned* data = bkt_data + (size_t)b * CAP;
    for (int i = threadIdx.x; i < cnt; i += 256) {
        atomicAdd(&hist[data[i] >> 17], 1);
    }
    __syncthreads();
    if (threadIdx.x < 64) {
        int node = b * 64 + threadIdx.x;
        if (node < N) dinv[node] = rsqrtf((float)(hist[threadIdx.x] + 1));
    }
}

// ---------------- GCN layers ----------------

// layer1: u[i][f] = x[i] * dinv[i] * W1[f]   (W1 is [1,32])
__global__ void l1_kernel(const float* __restrict__ x, const float* __restrict__ W1,
                          const float* __restrict__ dinv, float* __restrict__ u, int n) {
    int t = blockIdx.x * blockDim.x + threadIdx.x;
    int node = t >> 5, f = t & 31;
    if (node < n) u[t] = x[node] * dinv[node] * W1[f];
}

// u[i][f] = dinv[i] * sum_k h[i][k]*W[k][f]   (32 lanes per node, W in LDS)
__global__ void gemm_scale_kernel(const float* __restrict__ h, const float* __restrict__ W,
                                  const float* __restrict__ dinv, float* __restrict__ u, int n) {
    __shared__ float sW[1024];
    for (int i = threadIdx.x; i < 1024; i += 256) sW[i] = W[i];
    __syncthreads();
    int t = blockIdx.x * 256 + threadIdx.x;
    int node = t >> 5;
    int lane = threadIdx.x & 63;
    int f = lane & 31, base = lane & 32;
    if (node >= n) return;
    float hv = h[node * 32 + f];
    float acc = 0.f;
#pragma unroll
    for (int k = 0; k < 32; k++) {
        acc += __shfl(hv, base | k, 64) * sW[k * 32 + f];
    }
    u[node * 32 + f] = acc * dinv[node];
}

// bucket-centric aggregation: LDS accumulator 64 nodes x 32 features (8 KB).
// h_out[d][f] = relu(dinv[d]*(sum_{src->d} u[src][f] + u[d][f]) + b[f])
__global__ void agg_bucket_kernel(const float* __restrict__ u, const int* __restrict__ bkt_cnt,
                                  const unsigned* __restrict__ bkt_data,
                                  const float* __restrict__ dinv, const float* __restrict__ bias,
                                  float* __restrict__ hout, int N, int CAP) {
    __shared__ float acc[64 * 32];
    for (int i = threadIdx.x; i < 2048; i += 256) acc[i] = 0.f;
    __syncthreads();
    int b = blockIdx.x;
    int cnt = min(bkt_cnt[b], CAP);
    const unsigned* data = bkt_data + (size_t)b * CAP;
    int f = threadIdx.x & 31;
    int grp = threadIdx.x >> 5;  // 8 edge-groups of 32 lanes
    for (int e = grp; e < cnt; e += 8) {
        unsigned pk = data[e];
        int s = pk & 0x1FFFF;
        int ld = pk >> 17;
        atomicAdd(&acc[ld * 32 + f], u[(size_t)s * 32 + f]);
    }
    __syncthreads();
    int base = b * 64;
    for (int i = threadIdx.x; i < 2048; i += 256) {
        int ln = i >> 5, ff = i & 31;
        int node = base + ln;
        if (node < N) {
            float v = dinv[node] * (acc[i] + u[(size_t)node * 32 + ff]) + bias[ff];
            hout[(size_t)node * 32 + ff] = fmaxf(v, 0.f);
        }
    }
}

// ---------------- heads ----------------

__global__ void theta_kernel(const float* __restrict__ h, const float* __restrict__ Wt1,
                             const float* __restrict__ bt1, const float* __restrict__ Wt2,
                             const float* __restrict__ bt2, float* __restrict__ theta, int n) {
    __shared__ float sW[1024];
    __shared__ float sb[32];
    __shared__ float sw2[32];
    for (int i = threadIdx.x; i < 1024; i += 256) sW[i] = Wt1[i];
    if (threadIdx.x < 32) { sb[threadIdx.x] = bt1[threadIdx.x]; sw2[threadIdx.x] = Wt2[threadIdx.x]; }
    __syncthreads();
    int t = blockIdx.x * 256 + threadIdx.x;
    int node = t >> 5;
    int lane = threadIdx.x & 63;
    int f = lane & 31, base = lane & 32;
    if (node >= n) return;
    float hv = h[node * 32 + f];
    float a = sb[f];
#pragma unroll
    for (int k = 0; k < 32; k++) a += __shfl(hv, base | k, 64) * sW[k * 32 + f];
    a = fmaxf(a, 0.f) * sw2[f];
    a += __shfl_xor(a, 1, 64);
    a += __shfl_xor(a, 2, 64);
    a += __shfl_xor(a, 4, 64);
    a += __shfl_xor(a, 8, 64);
    a += __shfl_xor(a, 16, 64);
    if (f == 0) {
        float s = a + bt2[0];
        theta[node] = PI_F / (1.f + __expf(-s));
    }
}

// sorted-batch run-length pooling: 8 sub-chunks of 128 nodes per block, 32 lanes = features
__global__ void pool_kernel(const float* __restrict__ h, const int* __restrict__ batch,
                            float* __restrict__ gsum, float* __restrict__ gcnt, int n) {
    int f = threadIdx.x & 31;
    int sub = threadIdx.x >> 5;
    int start = blockIdx.x * 1024 + sub * 128;
    int end = min(start + 128, n);
    if (start >= end) return;
    int curg = batch[start];
    float acc = 0.f;
    int cnt = 0;
    for (int i = start; i < end; i++) {
        int g = batch[i];
        if (g != curg) {
            atomicAdd(&gsum[curg * 32 + f], acc);
            if (f == 0) atomicAdd(&gcnt[curg], (float)cnt);
            acc = 0.f; cnt = 0; curg = g;
        }
        acc += h[i * 32 + f];
        cnt++;
    }
    atomicAdd(&gsum[curg * 32 + f], acc);
    if (f == 0) atomicAdd(&gcnt[curg], (float)cnt);
}

__global__ void bg_kernel(const float* __restrict__ gsum, const float* __restrict__ gcnt,
                          const float* __restrict__ Wg1, const float* __restrict__ bg1,
                          const float* __restrict__ Wg2, const float* __restrict__ bg2,
                          float* __restrict__ out, int G) {
    __shared__ float sW[1024];
    for (int i = threadIdx.x; i < 1024; i += 256) sW[i] = Wg1[i];
    __syncthreads();
    int t = blockIdx.x * 256 + threadIdx.x;
    int g = t >> 5;
    int lane = threadIdx.x & 63;
    int f = lane & 31, base = lane & 32;
    if (g >= G) return;
    float cnt = fmaxf(gcnt[g], 1.f);
    float hv = gsum[g * 32 + f] / cnt;
    float a = bg1[f];
#pragma unroll
    for (int k = 0; k < 32; k++) a += __shfl(hv, base | k, 64) * sW[k * 32 + f];
    a = fmaxf(a, 0.f);
    float p0 = a * Wg2[f * 2 + 0];
    float p1 = a * Wg2[f * 2 + 1];
    for (int m = 1; m < 32; m <<= 1) {
        p0 += __shfl_xor(p0, m, 64);
        p1 += __shfl_xor(p1, m, 64);
    }
    if (f == 0) {
        out[g * 2 + 0] = 2.f * PI_F / (1.f + __expf(-(p0 + bg2[0])));
        out[g * 2 + 1] = 2.f * PI_F / (1.f + __expf(-(p1 + bg2[1])));
    }
}

// ---------------- launch ----------------

extern "C" void kernel_launch(void* const* d_in, const int* in_sizes, int n_in,
                              void* d_out, int out_size, void* d_ws, size_t ws_size,
                              hipStream_t stream) {
    const float* x   = (const float*)d_in[0];
    const int*   ei  = (const int*)d_in[1];
    const int* batch = (const int*)d_in[2];
    const float* W1  = (const float*)d_in[3];
    const float* b1  = (const float*)d_in[4];
    const float* W2  = (const float*)d_in[5];
    const float* b2  = (const float*)d_in[6];
    const float* W3  = (const float*)d_in[7];
    const float* b3  = (const float*)d_in[8];
    const float* Wt1 = (const float*)d_in[9];
    const float* bt1 = (const float*)d_in[10];
    const float* Wt2 = (const float*)d_in[11];
    const float* bt2 = (const float*)d_in[12];
    const float* Wg1 = (const float*)d_in[13];
    const float* bg1 = (const float*)d_in[14];
    const float* Wg2 = (const float*)d_in[15];
    const float* bg2 = (const float*)d_in[16];

    const int N = in_sizes[0];
    const int E = in_sizes[1] / 2;
    const int G = 128;
    const int* src = ei;
    const int* dst = ei + E;
    float* theta_out = (float*)d_out;
    float* bg_out = (float*)d_out + N;

    const int NBUCK = (N + 63) / 64;
    int avg = (E + NBUCK - 1) / NBUCK;
    const int CAP = ((avg + avg / 4 + 192) + 63) & ~63;  // ~+16 sigma headroom

    char* w = (char*)d_ws;
    auto alloc = [&](size_t bytes) -> char* { char* p = w; w += align256(bytes); return p; };
    int*      bkt_cnt  = (int*)alloc((size_t)NBUCK * 4);
    unsigned* bkt_data = (unsigned*)alloc((size_t)NBUCK * CAP * 4);
    float*    dinv     = (float*)alloc((size_t)N * 4);
    float*    bufA     = (float*)alloc((size_t)N * 32 * 4);
    float*    bufB     = (float*)alloc((size_t)N * 32 * 4);
    float*    gsum     = (float*)alloc((size_t)G * 32 * 4);
    float*    gcnt     = (float*)alloc((size_t)G * 4);

    hipMemsetAsync(bkt_cnt, 0, (size_t)NBUCK * 4, stream);
    hipMemsetAsync(gsum, 0, (size_t)G * 32 * 4, stream);
    hipMemsetAsync(gcnt, 0, (size_t)G * 4, stream);

    bucket_fill_kernel<<<(E + 255) / 256, 256, 0, stream>>>(src, dst, bkt_cnt, bkt_data, E, CAP);
    deg_kernel<<<NBUCK, 256, 0, stream>>>(bkt_cnt, bkt_data, dinv, N, CAP);

    unsigned gridNF = (unsigned)(((size_t)N * 32 + 255) / 256);  // 32 lanes/node

    // layer 1
    l1_kernel<<<gridNF, 256, 0, stream>>>(x, W1, dinv, bufB, N);
    agg_bucket_kernel<<<NBUCK, 256, 0, stream>>>(bufB, bkt_cnt, bkt_data, dinv, b1, bufA, N, CAP);
    // layer 2
    gemm_scale_kernel<<<gridNF, 256, 0, stream>>>(bufA, W2, dinv, bufB, N);
    agg_bucket_kernel<<<NBUCK, 256, 0, stream>>>(bufB, bkt_cnt, bkt_data, dinv, b2, bufA, N, CAP);
    // layer 3
    gemm_scale_kernel<<<gridNF, 256, 0, stream>>>(bufA, W3, dinv, bufB, N);
    agg_bucket_kernel<<<NBUCK, 256, 0, stream>>>(bufB, bkt_cnt, bkt_data, dinv, b3, bufA, N, CAP);

    // heads
    theta_kernel<<<gridNF, 256, 0, stream>>>(bufA, Wt1, bt1, Wt2, bt2, theta_out, N);
    pool_kernel<<<(N + 1023) / 1024, 256, 0, stream>>>(bufA, batch, gsum, gcnt, N);
    bg_kernel<<<(G * 32 + 255) / 256, 256, 0, stream>>>(gsum, gcnt, Wg1, bg1, Wg2, bg2, bg_out, G);
}

// Round 3
// 1025.606 us; speedup vs baseline: 2.5234x; 2.5234x over previous
//
#include <hip/hip_runtime.h>
#include <hip/hip_bf16.h>

#define PI_F 3.14159265358979323846f

static inline size_t align256(size_t x) { return (x + 255) & ~size_t(255); }

// ---------------- bucketed CSR build ----------------
// Buckets of 64 consecutive dst nodes. Edge packed as (local_dst<<17)|src
// (src < 2^17 since N=100000; local_dst < 64). Bump-allocated positions are
// sequential within a bucket -> stores write-combine in L2 (vs 195 MB
// write-allocate for the fully random scatter of a global CSR fill).

__global__ void bucket_fill_kernel(const int* __restrict__ src, const int* __restrict__ dst,
                                   int* __restrict__ bkt_cnt, unsigned* __restrict__ bkt_data,
                                   int E, int CAP) {
    int e = blockIdx.x * 256 + threadIdx.x;
    if (e >= E) return;
    int d = dst[e];
    int b = d >> 6;
    int p = atomicAdd(&bkt_cnt[b], 1);
    if (p < CAP) bkt_data[(size_t)b * CAP + p] = ((unsigned)(d & 63) << 17) | (unsigned)src[e];
}

// One block per bucket: LDS counting sort of <=CAP edges, in-place rewrite of
// the bucket region into dst-grouped src lists; emits e_start/e_cnt/dinv.
__global__ void csr_build_kernel(const int* __restrict__ bkt_cnt, unsigned* __restrict__ bkt_data,
                                 int* __restrict__ e_start, int* __restrict__ e_cnt,
                                 float* __restrict__ dinv, int N, int CAP) {
    extern __shared__ unsigned sdata[];   // CAP entries
    __shared__ int hist[64];
    __shared__ int bump[64];
    int b = blockIdx.x;
    if (threadIdx.x < 64) hist[threadIdx.x] = 0;
    __syncthreads();
    int cnt = min(bkt_cnt[b], CAP);
    unsigned* data = bkt_data + (size_t)b * CAP;
    for (int i = threadIdx.x; i < cnt; i += 256) {
        unsigned pk = data[i];
        sdata[i] = pk;
        atomicAdd(&hist[pk >> 17], 1);
    }
    __syncthreads();
    if (threadIdx.x < 64) {
        int orig = hist[threadIdx.x];
        int v = orig;
        // inclusive scan over 64 lanes (threads 0..63 are wave 0)
        for (int off = 1; off < 64; off <<= 1) {
            int w = __shfl_up(v, off, 64);
            if (threadIdx.x >= (unsigned)off) v += w;
        }
        int excl = v - orig;
        bump[threadIdx.x] = excl;
        int node = b * 64 + threadIdx.x;
        if (node < N) {
            dinv[node] = rsqrtf((float)(orig + 1));
            e_start[node] = b * CAP + excl;
            e_cnt[node] = orig;
        }
    }
    __syncthreads();
    for (int i = threadIdx.x; i < cnt; i += 256) {
        unsigned pk = sdata[i];
        int p = atomicAdd(&bump[pk >> 17], 1);
        data[p] = pk & 0x1FFFFu;   // now plain src index, dst-grouped
    }
}

// ---------------- GCN layers ----------------

// layer1: u[i][f] = x[i] * dinv[i] * W1[f]   (W1 is [1,32])
__global__ void l1_kernel(const float* __restrict__ x, const float* __restrict__ W1,
                          const float* __restrict__ dinv, float* __restrict__ u, int n) {
    int t = blockIdx.x * blockDim.x + threadIdx.x;
    int node = t >> 5, f = t & 31;
    if (node < n) u[t] = x[node] * dinv[node] * W1[f];
}

// u[i][f] = dinv[i] * sum_k h[i][k]*W[k][f]   (32 lanes per node, W in LDS)
__global__ void gemm_scale_kernel(const float* __restrict__ h, const float* __restrict__ W,
                                  const float* __restrict__ dinv, float* __restrict__ u, int n) {
    __shared__ float sW[1024];
    for (int i = threadIdx.x; i < 1024; i += 256) sW[i] = W[i];
    __syncthreads();
    int t = blockIdx.x * 256 + threadIdx.x;
    int node = t >> 5;
    int lane = threadIdx.x & 63;
    int f = lane & 31, base = lane & 32;
    if (node >= n) return;
    float hv = h[node * 32 + f];
    float acc = 0.f;
#pragma unroll
    for (int k = 0; k < 32; k++) {
        acc += __shfl(hv, base | k, 64) * sW[k * 32 + f];
    }
    u[node * 32 + f] = acc * dinv[node];
}

// h_out[d][f] = relu(dinv[d]*(sum_{src in N(d)} u[src][f] + u[d][f]) + b[f])
// one 64-lane wave per node: halves split the edge list, 32 lanes = features
__global__ void agg_kernel(const float* __restrict__ u, const int* __restrict__ e_start,
                           const int* __restrict__ e_cnt, const unsigned* __restrict__ csr,
                           const float* __restrict__ dinv, const float* __restrict__ bias,
                           float* __restrict__ hout, int n) {
    int t = blockIdx.x * 256 + threadIdx.x;
    int d = t >> 6;
    int lane = threadIdx.x & 63;
    int f = lane & 31, half = lane >> 5;
    if (d >= n) return;
    int e0 = e_start[d];
    int e1 = e0 + e_cnt[d];
    float acc0 = 0.f, acc1 = 0.f;
    int j = e0 + half;
    for (; j + 2 < e1; j += 4) {
        int s0 = (int)csr[j];
        int s1 = (int)csr[j + 2];
        acc0 += u[(size_t)s0 * 32 + f];
        acc1 += u[(size_t)s1 * 32 + f];
    }
    if (j < e1) acc0 += u[(size_t)csr[j] * 32 + f];
    float acc = acc0 + acc1;
    acc += __shfl_xor(acc, 32, 64);
    if (half == 0) {
        float v = dinv[d] * (acc + u[(size_t)d * 32 + f]) + bias[f];
        hout[(size_t)d * 32 + f] = fmaxf(v, 0.f);
    }
}

// ---------------- heads ----------------

__global__ void theta_kernel(const float* __restrict__ h, const float* __restrict__ Wt1,
                             const float* __restrict__ bt1, const float* __restrict__ Wt2,
                             const float* __restrict__ bt2, float* __restrict__ theta, int n) {
    __shared__ float sW[1024];
    __shared__ float sb[32];
    __shared__ float sw2[32];
    for (int i = threadIdx.x; i < 1024; i += 256) sW[i] = Wt1[i];
    if (threadIdx.x < 32) { sb[threadIdx.x] = bt1[threadIdx.x]; sw2[threadIdx.x] = Wt2[threadIdx.x]; }
    __syncthreads();
    int t = blockIdx.x * 256 + threadIdx.x;
    int node = t >> 5;
    int lane = threadIdx.x & 63;
    int f = lane & 31, base = lane & 32;
    if (node >= n) return;
    float hv = h[node * 32 + f];
    float a = sb[f];
#pragma unroll
    for (int k = 0; k < 32; k++) a += __shfl(hv, base | k, 64) * sW[k * 32 + f];
    a = fmaxf(a, 0.f) * sw2[f];
    a += __shfl_xor(a, 1, 64);
    a += __shfl_xor(a, 2, 64);
    a += __shfl_xor(a, 4, 64);
    a += __shfl_xor(a, 8, 64);
    a += __shfl_xor(a, 16, 64);
    if (f == 0) {
        float s = a + bt2[0];
        theta[node] = PI_F / (1.f + __expf(-s));
    }
}

// sorted-batch run-length pooling: 8 sub-chunks of 128 nodes per block, 32 lanes = features
__global__ void pool_kernel(const float* __restrict__ h, const int* __restrict__ batch,
                            float* __restrict__ gsum, float* __restrict__ gcnt, int n) {
    int f = threadIdx.x & 31;
    int sub = threadIdx.x >> 5;
    int start = blockIdx.x * 1024 + sub * 128;
    int end = min(start + 128, n);
    if (start >= end) return;
    int curg = batch[start];
    float acc = 0.f;
    int cnt = 0;
    for (int i = start; i < end; i++) {
        int g = batch[i];
        if (g != curg) {
            atomicAdd(&gsum[curg * 32 + f], acc);
            if (f == 0) atomicAdd(&gcnt[curg], (float)cnt);
            acc = 0.f; cnt = 0; curg = g;
        }
        acc += h[i * 32 + f];
        cnt++;
    }
    atomicAdd(&gsum[curg * 32 + f], acc);
    if (f == 0) atomicAdd(&gcnt[curg], (float)cnt);
}

__global__ void bg_kernel(const float* __restrict__ gsum, const float* __restrict__ gcnt,
                          const float* __restrict__ Wg1, const float* __restrict__ bg1,
                          const float* __restrict__ Wg2, const float* __restrict__ bg2,
                          float* __restrict__ out, int G) {
    __shared__ float sW[1024];
    for (int i = threadIdx.x; i < 1024; i += 256) sW[i] = Wg1[i];
    __syncthreads();
    int t = blockIdx.x * 256 + threadIdx.x;
    int g = t >> 5;
    int lane = threadIdx.x & 63;
    int f = lane & 31, base = lane & 32;
    if (g >= G) return;
    float cnt = fmaxf(gcnt[g], 1.f);
    float hv = gsum[g * 32 + f] / cnt;
    float a = bg1[f];
#pragma unroll
    for (int k = 0; k < 32; k++) a += __shfl(hv, base | k, 64) * sW[k * 32 + f];
    a = fmaxf(a, 0.f);
    float p0 = a * Wg2[f * 2 + 0];
    float p1 = a * Wg2[f * 2 + 1];
    for (int m = 1; m < 32; m <<= 1) {
        p0 += __shfl_xor(p0, m, 64);
        p1 += __shfl_xor(p1, m, 64);
    }
    if (f == 0) {
        out[g * 2 + 0] = 2.f * PI_F / (1.f + __expf(-(p0 + bg2[0])));
        out[g * 2 + 1] = 2.f * PI_F / (1.f + __expf(-(p1 + bg2[1])));
    }
}

// ---------------- launch ----------------

extern "C" void kernel_launch(void* const* d_in, const int* in_sizes, int n_in,
                              void* d_out, int out_size, void* d_ws, size_t ws_size,
                              hipStream_t stream) {
    const float* x   = (const float*)d_in[0];
    const int*   ei  = (const int*)d_in[1];
    const int* batch = (const int*)d_in[2];
    const float* W1  = (const float*)d_in[3];
    const float* b1  = (const float*)d_in[4];
    const float* W2  = (const float*)d_in[5];
    const float* b2  = (const float*)d_in[6];
    const float* W3  = (const float*)d_in[7];
    const float* b3  = (const float*)d_in[8];
    const float* Wt1 = (const float*)d_in[9];
    const float* bt1 = (const float*)d_in[10];
    const float* Wt2 = (const float*)d_in[11];
    const float* bt2 = (const float*)d_in[12];
    const float* Wg1 = (const float*)d_in[13];
    const float* bg1 = (const float*)d_in[14];
    const float* Wg2 = (const float*)d_in[15];
    const float* bg2 = (const float*)d_in[16];

    const int N = in_sizes[0];
    const int E = in_sizes[1] / 2;
    const int G = 128;
    const int* src = ei;
    const int* dst = ei + E;
    float* theta_out = (float*)d_out;
    float* bg_out = (float*)d_out + N;

    const int NBUCK = (N + 63) / 64;
    int avg = (E + NBUCK - 1) / NBUCK;
    const int CAP = ((avg + avg / 4 + 192) + 63) & ~63;  // ~+16 sigma headroom

    char* w = (char*)d_ws;
    auto alloc = [&](size_t bytes) -> char* { char* p = w; w += align256(bytes); return p; };
    int*      bkt_cnt  = (int*)alloc((size_t)NBUCK * 4);
    unsigned* bkt_data = (unsigned*)alloc((size_t)NBUCK * CAP * 4);
    int*      e_start  = (int*)alloc((size_t)N * 4);
    int*      e_cnt    = (int*)alloc((size_t)N * 4);
    float*    dinv     = (float*)alloc((size_t)N * 4);
    float*    bufA     = (float*)alloc((size_t)N * 32 * 4);
    float*    bufB     = (float*)alloc((size_t)N * 32 * 4);
    float*    gsum     = (float*)alloc((size_t)G * 32 * 4);
    float*    gcnt     = (float*)alloc((size_t)G * 4);

    hipMemsetAsync(bkt_cnt, 0, (size_t)NBUCK * 4, stream);
    hipMemsetAsync(gsum, 0, (size_t)G * 32 * 4, stream);
    hipMemsetAsync(gcnt, 0, (size_t)G * 4, stream);

    bucket_fill_kernel<<<(E + 255) / 256, 256, 0, stream>>>(src, dst, bkt_cnt, bkt_data, E, CAP);
    csr_build_kernel<<<NBUCK, 256, (size_t)CAP * 4, stream>>>(bkt_cnt, bkt_data, e_start, e_cnt, dinv, N, CAP);

    unsigned gridNF = (unsigned)(((size_t)N * 32 + 255) / 256);  // 32 lanes/node
    unsigned gridNW = (unsigned)(((size_t)N * 64 + 255) / 256);  // 64 lanes/node

    // layer 1
    l1_kernel<<<gridNF, 256, 0, stream>>>(x, W1, dinv, bufB, N);
    agg_kernel<<<gridNW, 256, 0, stream>>>(bufB, e_start, e_cnt, bkt_data, dinv, b1, bufA, N);
    // layer 2
    gemm_scale_kernel<<<gridNF, 256, 0, stream>>>(bufA, W2, dinv, bufB, N);
    agg_kernel<<<gridNW, 256, 0, stream>>>(bufB, e_start, e_cnt, bkt_data, dinv, b2, bufA, N);
    // layer 3
    gemm_scale_kernel<<<gridNF, 256, 0, stream>>>(bufA, W3, dinv, bufB, N);
    agg_kernel<<<gridNW, 256, 0, stream>>>(bufB, e_start, e_cnt, bkt_data, dinv, b3, bufA, N);

    // heads
    theta_kernel<<<gridNF, 256, 0, stream>>>(bufA, Wt1, bt1, Wt2, bt2, theta_out, N);
    pool_kernel<<<(N + 1023) / 1024, 256, 0, stream>>>(bufA, batch, gsum, gcnt, N);
    bg_kernel<<<(G * 32 + 255) / 256, 256, 0, stream>>>(gsum, gcnt, Wg1, bg1, Wg2, bg2, bg_out, G);
}

// Round 4
// 610.434 us; speedup vs baseline: 4.2397x; 1.6801x over previous
//
#include <hip/hip_runtime.h>
#include <hip/hip_bf16.h>

#define PI_F 3.14159265358979323846f
#define NBLK 256   // blocks for count/scatter passes

static inline size_t align256(size_t x) { return (x + 255) & ~size_t(255); }

// ---------------- atomic-free bucketed CSR build ----------------
// Level 1: counting sort into buckets of 64 consecutive dst (NBUCK buckets),
// exact offsets from a [NBLK x NBUCK] count matrix — no global atomics.
// Level 2: per-bucket LDS counting sort -> dst-grouped CSR.
// Edge packed as (local_dst<<17)|src  (src < 2^17, local_dst < 64).

__global__ void count_kernel(const int* __restrict__ dst, int* __restrict__ C,
                             int E, int CHUNK, int NBUCK) {
    extern __shared__ int hist[];   // NBUCK ints
    for (int i = threadIdx.x; i < NBUCK; i += 256) hist[i] = 0;
    __syncthreads();
    int s0 = blockIdx.x * CHUNK, s1 = min(s0 + CHUNK, E);
    for (int e = s0 + threadIdx.x; e < s1; e += 256)
        atomicAdd(&hist[dst[e] >> 6], 1);
    __syncthreads();
    for (int i = threadIdx.x; i < NBUCK; i += 256)
        C[(size_t)blockIdx.x * NBUCK + i] = hist[i];
}

// per-bucket exclusive scan over blocks (in place), emit column totals
__global__ void scan_blocks_kernel(int* __restrict__ C, int* __restrict__ colsum, int NBUCK) {
    __shared__ int s[256];
    int k = blockIdx.x;
    int b = threadIdx.x;
    int v = C[(size_t)b * NBUCK + k];
    s[b] = v;
    __syncthreads();
    for (int off = 1; off < 256; off <<= 1) {
        int w = (b >= off) ? s[b - off] : 0;
        __syncthreads();
        s[b] += w;
        __syncthreads();
    }
    C[(size_t)b * NBUCK + k] = s[b] - v;   // exclusive
    if (b == 255) colsum[k] = s[255];
}

// scan bucket totals -> bbase (exclusive), bbase[NBUCK]=E
__global__ void scan_totals_kernel(const int* __restrict__ colsum, int* __restrict__ bbase,
                                   int NBUCK, int E) {
    __shared__ int s[256];
    __shared__ int running;
    if (threadIdx.x == 0) running = 0;
    __syncthreads();
    for (int base = 0; base < NBUCK; base += 256) {
        int i = base + threadIdx.x;
        int v = (i < NBUCK) ? colsum[i] : 0;
        s[threadIdx.x] = v;
        __syncthreads();
        for (int off = 1; off < 256; off <<= 1) {
            int w = (threadIdx.x >= (unsigned)off) ? s[threadIdx.x - off] : 0;
            __syncthreads();
            s[threadIdx.x] += w;
            __syncthreads();
        }
        if (i < NBUCK) bbase[i] = running + s[threadIdx.x] - v;
        __syncthreads();
        if (threadIdx.x == 255) running += s[255];
        __syncthreads();
    }
    if (threadIdx.x == 0) bbase[NBUCK] = E;
}

__global__ void scatter_kernel(const int* __restrict__ src, const int* __restrict__ dst,
                               const int* __restrict__ C, const int* __restrict__ bbase,
                               unsigned* __restrict__ bkt_data, int E, int CHUNK, int NBUCK) {
    extern __shared__ int ofs[];   // NBUCK ints: this block's bump allocators
    for (int i = threadIdx.x; i < NBUCK; i += 256)
        ofs[i] = bbase[i] + C[(size_t)blockIdx.x * NBUCK + i];
    __syncthreads();
    int s0 = blockIdx.x * CHUNK, s1 = min(s0 + CHUNK, E);
    for (int e = s0 + threadIdx.x; e < s1; e += 256) {
        int d = dst[e];
        int p = atomicAdd(&ofs[d >> 6], 1);   // LDS atomic only
        bkt_data[p] = ((unsigned)(d & 63) << 17) | (unsigned)src[e];
    }
}

// one block per bucket: counting sort by local dst -> csr (plain src), e_start/e_cnt/dinv
__global__ void csr_build_kernel(const unsigned* __restrict__ bkt_data, const int* __restrict__ bbase,
                                 unsigned* __restrict__ csr, int* __restrict__ e_start,
                                 int* __restrict__ e_cnt, float* __restrict__ dinv, int N) {
    __shared__ int hist[64];
    __shared__ int bump[64];
    int b = blockIdx.x;
    int g0 = bbase[b], g1 = bbase[b + 1];
    if (threadIdx.x < 64) hist[threadIdx.x] = 0;
    __syncthreads();
    for (int i = g0 + threadIdx.x; i < g1; i += 256)
        atomicAdd(&hist[bkt_data[i] >> 17], 1);
    __syncthreads();
    if (threadIdx.x < 64) {
        int orig = hist[threadIdx.x];
        int v = orig;
        for (int off = 1; off < 64; off <<= 1) {   // wave-0 inclusive scan
            int w = __shfl_up(v, off, 64);
            if ((int)threadIdx.x >= off) v += w;
        }
        int excl = v - orig;
        bump[threadIdx.x] = g0 + excl;
        int node = b * 64 + threadIdx.x;
        if (node < N) {
            dinv[node] = rsqrtf((float)(orig + 1));
            e_start[node] = g0 + excl;
            e_cnt[node] = orig;
        }
    }
    __syncthreads();
    for (int i = g0 + threadIdx.x; i < g1; i += 256) {
        unsigned pk = bkt_data[i];
        int p = atomicAdd(&bump[pk >> 17], 1);
        csr[p] = pk & 0x1FFFFu;
    }
}

// ---------------- GCN layers ----------------

// layer1: u[i][f] = x[i] * dinv[i] * W1[f]   (W1 is [1,32])
__global__ void l1_kernel(const float* __restrict__ x, const float* __restrict__ W1,
                          const float* __restrict__ dinv, float* __restrict__ u, int n) {
    int t = blockIdx.x * blockDim.x + threadIdx.x;
    int node = t >> 5, f = t & 31;
    if (node < n) u[t] = x[node] * dinv[node] * W1[f];
}

// Aggregation, one 64-lane wave per dst node; halves split the edge list.
// fuse=0: out = relu(dinv*(sum u[src] + u[self]) + bias)            [= h]
// fuse=1: out = dinv * (relu(...) @ W)                              [= next-layer u]
__global__ void agg_kernel(const float* __restrict__ u, const int* __restrict__ e_start,
                           const int* __restrict__ e_cnt, const unsigned* __restrict__ csr,
                           const float* __restrict__ dinv, const float* __restrict__ bias,
                           const float* __restrict__ W, float* __restrict__ out,
                           int n, int fuse) {
    __shared__ float sW[1024];
    if (fuse) {
        for (int i = threadIdx.x; i < 1024; i += 256) sW[i] = W[i];
        __syncthreads();
    }
    int t = blockIdx.x * 256 + threadIdx.x;
    int d = t >> 6;
    int lane = threadIdx.x & 63;
    int f = lane & 31, half = lane >> 5;
    if (d >= n) return;
    int e0 = e_start[d];
    int e1 = e0 + e_cnt[d];
    float a0 = 0.f, a1 = 0.f;
    int j = e0 + half;
    for (; j + 2 < e1; j += 4) {
        int s0 = (int)csr[j];
        int s1 = (int)csr[j + 2];
        a0 += u[(size_t)s0 * 32 + f];
        a1 += u[(size_t)s1 * 32 + f];
    }
    if (j < e1) a0 += u[(size_t)csr[j] * 32 + f];
    float acc = a0 + a1;
    acc += __shfl_xor(acc, 32, 64);            // both halves now hold full sum
    float dv = dinv[d];
    float v = fmaxf(dv * (acc + u[(size_t)d * 32 + f]) + bias[f], 0.f);  // replicated
    if (fuse) {
        float p = 0.f;
        int k0 = half << 4;                    // split-k: half 0 -> k=0..15, half 1 -> 16..31
#pragma unroll
        for (int k = 0; k < 16; k++) p += __shfl(v, k0 + k, 64) * sW[(k0 + k) * 32 + f];
        p += __shfl_xor(p, 32, 64);
        if (half == 0) out[(size_t)d * 32 + f] = dv * p;
    } else {
        if (half == 0) out[(size_t)d * 32 + f] = v;
    }
}

// ---------------- heads ----------------

__global__ void theta_kernel(const float* __restrict__ h, const float* __restrict__ Wt1,
                             const float* __restrict__ bt1, const float* __restrict__ Wt2,
                             const float* __restrict__ bt2, float* __restrict__ theta, int n) {
    __shared__ float sW[1024];
    __shared__ float sb[32];
    __shared__ float sw2[32];
    for (int i = threadIdx.x; i < 1024; i += 256) sW[i] = Wt1[i];
    if (threadIdx.x < 32) { sb[threadIdx.x] = bt1[threadIdx.x]; sw2[threadIdx.x] = Wt2[threadIdx.x]; }
    __syncthreads();
    int t = blockIdx.x * 256 + threadIdx.x;
    int node = t >> 5;
    int lane = threadIdx.x & 63;
    int f = lane & 31, base = lane & 32;
    if (node >= n) return;
    float hv = h[node * 32 + f];
    float a = sb[f];
#pragma unroll
    for (int k = 0; k < 32; k++) a += __shfl(hv, base | k, 64) * sW[k * 32 + f];
    a = fmaxf(a, 0.f) * sw2[f];
    a += __shfl_xor(a, 1, 64);
    a += __shfl_xor(a, 2, 64);
    a += __shfl_xor(a, 4, 64);
    a += __shfl_xor(a, 8, 64);
    a += __shfl_xor(a, 16, 64);
    if (f == 0) {
        float s = a + bt2[0];
        theta[node] = PI_F / (1.f + __expf(-s));
    }
}

__global__ void pool_kernel(const float* __restrict__ h, const int* __restrict__ batch,
                            float* __restrict__ gsum, float* __restrict__ gcnt, int n) {
    int f = threadIdx.x & 31;
    int sub = threadIdx.x >> 5;
    int start = blockIdx.x * 1024 + sub * 128;
    int end = min(start + 128, n);
    if (start >= end) return;
    int curg = batch[start];
    float acc = 0.f;
    int cnt = 0;
    for (int i = start; i < end; i++) {
        int g = batch[i];
        if (g != curg) {
            atomicAdd(&gsum[curg * 32 + f], acc);
            if (f == 0) atomicAdd(&gcnt[curg], (float)cnt);
            acc = 0.f; cnt = 0; curg = g;
        }
        acc += h[i * 32 + f];
        cnt++;
    }
    atomicAdd(&gsum[curg * 32 + f], acc);
    if (f == 0) atomicAdd(&gcnt[curg], (float)cnt);
}

__global__ void bg_kernel(const float* __restrict__ gsum, const float* __restrict__ gcnt,
                          const float* __restrict__ Wg1, const float* __restrict__ bg1,
                          const float* __restrict__ Wg2, const float* __restrict__ bg2,
                          float* __restrict__ out, int G) {
    __shared__ float sW[1024];
    for (int i = threadIdx.x; i < 1024; i += 256) sW[i] = Wg1[i];
    __syncthreads();
    int t = blockIdx.x * 256 + threadIdx.x;
    int g = t >> 5;
    int lane = threadIdx.x & 63;
    int f = lane & 31, base = lane & 32;
    if (g >= G) return;
    float cnt = fmaxf(gcnt[g], 1.f);
    float hv = gsum[g * 32 + f] / cnt;
    float a = bg1[f];
#pragma unroll
    for (int k = 0; k < 32; k++) a += __shfl(hv, base | k, 64) * sW[k * 32 + f];
    a = fmaxf(a, 0.f);
    float p0 = a * Wg2[f * 2 + 0];
    float p1 = a * Wg2[f * 2 + 1];
    for (int m = 1; m < 32; m <<= 1) {
        p0 += __shfl_xor(p0, m, 64);
        p1 += __shfl_xor(p1, m, 64);
    }
    if (f == 0) {
        out[g * 2 + 0] = 2.f * PI_F / (1.f + __expf(-(p0 + bg2[0])));
        out[g * 2 + 1] = 2.f * PI_F / (1.f + __expf(-(p1 + bg2[1])));
    }
}

// ---------------- launch ----------------

extern "C" void kernel_launch(void* const* d_in, const int* in_sizes, int n_in,
                              void* d_out, int out_size, void* d_ws, size_t ws_size,
                              hipStream_t stream) {
    const float* x   = (const float*)d_in[0];
    const int*   ei  = (const int*)d_in[1];
    const int* batch = (const int*)d_in[2];
    const float* W1  = (const float*)d_in[3];
    const float* b1  = (const float*)d_in[4];
    const float* W2  = (const float*)d_in[5];
    const float* b2  = (const float*)d_in[6];
    const float* W3  = (const float*)d_in[7];
    const float* b3  = (const float*)d_in[8];
    const float* Wt1 = (const float*)d_in[9];
    const float* bt1 = (const float*)d_in[10];
    const float* Wt2 = (const float*)d_in[11];
    const float* bt2 = (const float*)d_in[12];
    const float* Wg1 = (const float*)d_in[13];
    const float* bg1 = (const float*)d_in[14];
    const float* Wg2 = (const float*)d_in[15];
    const float* bg2 = (const float*)d_in[16];

    const int N = in_sizes[0];
    const int E = in_sizes[1] / 2;
    const int G = 128;
    const int* src = ei;
    const int* dst = ei + E;
    float* theta_out = (float*)d_out;
    float* bg_out = (float*)d_out + N;

    const int NBUCK = (N + 63) / 64;
    const int CHUNK = (E + NBLK - 1) / NBLK;

    char* w = (char*)d_ws;
    auto alloc = [&](size_t bytes) -> char* { char* p = w; w += align256(bytes); return p; };
    int*      C        = (int*)alloc((size_t)NBLK * NBUCK * 4);
    int*      colsum   = (int*)alloc((size_t)NBUCK * 4);
    int*      bbase    = (int*)alloc((size_t)(NBUCK + 1) * 4);
    unsigned* bkt_data = (unsigned*)alloc((size_t)E * 4);
    unsigned* csr      = (unsigned*)alloc((size_t)E * 4);
    int*      e_start  = (int*)alloc((size_t)N * 4);
    int*      e_cnt    = (int*)alloc((size_t)N * 4);
    float*    dinv     = (float*)alloc((size_t)N * 4);
    float*    bufA     = (float*)alloc((size_t)N * 32 * 4);
    float*    bufB     = (float*)alloc((size_t)N * 32 * 4);
    float*    gsum     = (float*)alloc((size_t)G * 32 * 4);
    float*    gcnt     = (float*)alloc((size_t)G * 4);

    hipMemsetAsync(gsum, 0, (size_t)G * 32 * 4, stream);
    hipMemsetAsync(gcnt, 0, (size_t)G * 4, stream);

    size_t ldsB = (size_t)NBUCK * 4;
    count_kernel<<<NBLK, 256, ldsB, stream>>>(dst, C, E, CHUNK, NBUCK);
    scan_blocks_kernel<<<NBUCK, 256, 0, stream>>>(C, colsum, NBUCK);
    scan_totals_kernel<<<1, 256, 0, stream>>>(colsum, bbase, NBUCK, E);
    scatter_kernel<<<NBLK, 256, ldsB, stream>>>(src, dst, C, bbase, bkt_data, E, CHUNK, NBUCK);
    csr_build_kernel<<<NBUCK, 256, 0, stream>>>(bkt_data, bbase, csr, e_start, e_cnt, dinv, N);

    unsigned gridNF = (unsigned)(((size_t)N * 32 + 255) / 256);  // 32 lanes/node
    unsigned gridNW = (unsigned)(((size_t)N * 64 + 255) / 256);  // 64 lanes/node

    // layer 1 -> (fused W2 gemm) u2
    l1_kernel<<<gridNF, 256, 0, stream>>>(x, W1, dinv, bufB, N);
    agg_kernel<<<gridNW, 256, 0, stream>>>(bufB, e_start, e_cnt, csr, dinv, b1, W2, bufA, N, 1);
    // layer 2 -> (fused W3 gemm) u3
    agg_kernel<<<gridNW, 256, 0, stream>>>(bufA, e_start, e_cnt, csr, dinv, b2, W3, bufB, N, 1);
    // layer 3 -> h
    agg_kernel<<<gridNW, 256, 0, stream>>>(bufB, e_start, e_cnt, csr, dinv, b3, (const float*)nullptr, bufA, N, 0);

    // heads
    theta_kernel<<<gridNF, 256, 0, stream>>>(bufA, Wt1, bt1, Wt2, bt2, theta_out, N);
    pool_kernel<<<(N + 1023) / 1024, 256, 0, stream>>>(bufA, batch, gsum, gcnt, N);
    bg_kernel<<<(G * 32 + 255) / 256, 256, 0, stream>>>(gsum, gcnt, Wg1, bg1, Wg2, bg2, bg_out, G);
}

// Round 5
// 518.490 us; speedup vs baseline: 4.9915x; 1.1773x over previous
//
#include <hip/hip_runtime.h>
#include <hip/hip_bf16.h>

#define PI_F 3.14159265358979323846f
#define NBLK 256   // blocks for count/scatter passes

static inline size_t align256(size_t x) { return (x + 255) & ~size_t(255); }

// ---------------- atomic-free bucketed CSR build ----------------
// Level 1: counting sort into buckets of 64 consecutive dst (NBUCK buckets),
// exact offsets from a [NBLK x NBUCK] count matrix — no global atomics.
// Level 2: per-bucket LDS counting sort -> dst-grouped CSR.
// Edge packed as (local_dst<<17)|src  (src < 2^17, local_dst < 64).

__global__ void count_kernel(const int* __restrict__ dst, int* __restrict__ C,
                             int E, int CHUNK, int NBUCK) {
    extern __shared__ int hist[];   // NBUCK ints
    for (int i = threadIdx.x; i < NBUCK; i += 256) hist[i] = 0;
    __syncthreads();
    int s0 = blockIdx.x * CHUNK, s1 = min(s0 + CHUNK, E);
    for (int e = s0 + threadIdx.x; e < s1; e += 256)
        atomicAdd(&hist[dst[e] >> 6], 1);
    __syncthreads();
    for (int i = threadIdx.x; i < NBUCK; i += 256)
        C[(size_t)blockIdx.x * NBUCK + i] = hist[i];
}

// per-bucket exclusive scan over blocks (in place), emit column totals
__global__ void scan_blocks_kernel(int* __restrict__ C, int* __restrict__ colsum, int NBUCK) {
    __shared__ int s[256];
    int k = blockIdx.x;
    int b = threadIdx.x;
    int v = C[(size_t)b * NBUCK + k];
    s[b] = v;
    __syncthreads();
    for (int off = 1; off < 256; off <<= 1) {
        int w = (b >= off) ? s[b - off] : 0;
        __syncthreads();
        s[b] += w;
        __syncthreads();
    }
    C[(size_t)b * NBUCK + k] = s[b] - v;   // exclusive
    if (b == 255) colsum[k] = s[255];
}

// scan bucket totals -> bbase (exclusive), bbase[NBUCK]=E
__global__ void scan_totals_kernel(const int* __restrict__ colsum, int* __restrict__ bbase,
                                   int NBUCK, int E) {
    __shared__ int s[256];
    __shared__ int running;
    if (threadIdx.x == 0) running = 0;
    __syncthreads();
    for (int base = 0; base < NBUCK; base += 256) {
        int i = base + threadIdx.x;
        int v = (i < NBUCK) ? colsum[i] : 0;
        s[threadIdx.x] = v;
        __syncthreads();
        for (int off = 1; off < 256; off <<= 1) {
            int w = (threadIdx.x >= (unsigned)off) ? s[threadIdx.x - off] : 0;
            __syncthreads();
            s[threadIdx.x] += w;
            __syncthreads();
        }
        if (i < NBUCK) bbase[i] = running + s[threadIdx.x] - v;
        __syncthreads();
        if (threadIdx.x == 255) running += s[255];
        __syncthreads();
    }
    if (threadIdx.x == 0) bbase[NBUCK] = E;
}

__global__ void scatter_kernel(const int* __restrict__ src, const int* __restrict__ dst,
                               const int* __restrict__ C, const int* __restrict__ bbase,
                               unsigned* __restrict__ bkt_data, int E, int CHUNK, int NBUCK) {
    extern __shared__ int ofs[];   // NBUCK ints: this block's bump allocators
    for (int i = threadIdx.x; i < NBUCK; i += 256)
        ofs[i] = bbase[i] + C[(size_t)blockIdx.x * NBUCK + i];
    __syncthreads();
    int s0 = blockIdx.x * CHUNK, s1 = min(s0 + CHUNK, E);
    for (int e = s0 + threadIdx.x; e < s1; e += 256) {
        int d = dst[e];
        int p = atomicAdd(&ofs[d >> 6], 1);   // LDS atomic only
        bkt_data[p] = ((unsigned)(d & 63) << 17) | (unsigned)src[e];
    }
}

// one block per bucket: counting sort by local dst -> csr (plain src), e_start/e_cnt/dinv/xd
__global__ void csr_build_kernel(const unsigned* __restrict__ bkt_data, const int* __restrict__ bbase,
                                 const float* __restrict__ x,
                                 unsigned* __restrict__ csr, int* __restrict__ e_start,
                                 int* __restrict__ e_cnt, float* __restrict__ dinv,
                                 float* __restrict__ xd, int N) {
    __shared__ int hist[64];
    __shared__ int bump[64];
    int b = blockIdx.x;
    int g0 = bbase[b], g1 = bbase[b + 1];
    if (threadIdx.x < 64) hist[threadIdx.x] = 0;
    __syncthreads();
    for (int i = g0 + threadIdx.x; i < g1; i += 256)
        atomicAdd(&hist[bkt_data[i] >> 17], 1);
    __syncthreads();
    if (threadIdx.x < 64) {
        int orig = hist[threadIdx.x];
        int v = orig;
        for (int off = 1; off < 64; off <<= 1) {   // wave-0 inclusive scan
            int w = __shfl_up(v, off, 64);
            if ((int)threadIdx.x >= off) v += w;
        }
        int excl = v - orig;
        bump[threadIdx.x] = g0 + excl;
        int node = b * 64 + threadIdx.x;
        if (node < N) {
            float dv = rsqrtf((float)(orig + 1));
            dinv[node] = dv;
            xd[node] = x[node] * dv;
            e_start[node] = g0 + excl;
            e_cnt[node] = orig;
        }
    }
    __syncthreads();
    for (int i = g0 + threadIdx.x; i < g1; i += 256) {
        unsigned pk = bkt_data[i];
        int p = atomicAdd(&bump[pk >> 17], 1);
        csr[p] = pk & 0x1FFFFu;
    }
}

// ---------------- GCN layers ----------------

// Layer 1 is rank-1: u1[s][f] = xd[s]*W1[f]  =>  sum_src u1[src][f] = (sum xd[src])*W1[f].
// One wave per dst node: 64 lanes stride the edge list summing the SCALAR xd[src]
// (xd is 400 KB -> L2-resident), then epilogue h1=relu(t*W1+b1), fused @W2, u2 out (bf16).
__global__ void agg1_kernel(const float* __restrict__ xd, const int* __restrict__ e_start,
                            const int* __restrict__ e_cnt, const unsigned* __restrict__ csr,
                            const float* __restrict__ dinv,
                            const float* __restrict__ W1, const float* __restrict__ b1,
                            const float* __restrict__ W2,
                            __hip_bfloat16* __restrict__ u2out, int n) {
    __shared__ float sW2[1024];
    __shared__ float sW1[32], sb1[32];
    for (int i = threadIdx.x; i < 1024; i += 256) sW2[i] = W2[i];
    if (threadIdx.x < 32) { sW1[threadIdx.x] = W1[threadIdx.x]; sb1[threadIdx.x] = b1[threadIdx.x]; }
    __syncthreads();
    int t = blockIdx.x * 256 + threadIdx.x;
    int d = t >> 6;
    int lane = threadIdx.x & 63;
    if (d >= n) return;
    int e0 = e_start[d];
    int cnt = e_cnt[d];
    float s = 0.f;
    for (int j = lane; j < cnt; j += 64) s += xd[csr[e0 + j]];
#pragma unroll
    for (int m = 1; m < 64; m <<= 1) s += __shfl_xor(s, m, 64);
    float dv = dinv[d];
    float tt = dv * (s + xd[d]);
    int f = lane & 31, half = lane >> 5;
    float h1 = fmaxf(tt * sW1[f] + sb1[f], 0.f);   // replicated in both halves
    float p = 0.f;
    int k0 = half << 4;
#pragma unroll
    for (int k = 0; k < 16; k++) p += __shfl(h1, k0 + k, 64) * sW2[(k0 + k) * 32 + f];
    p += __shfl_xor(p, 32, 64);
    if (half == 0) u2out[(size_t)d * 32 + f] = __float2bfloat16(dv * p);
}

// Aggregation over bf16 u rows, one wave per dst; halves split the edge list.
// fuse=1: out_bf16 = dinv*(relu(...)@W)   fuse=0: out_f32 = relu(...)
__global__ void agg_kernel(const __hip_bfloat16* __restrict__ u, const int* __restrict__ e_start,
                           const int* __restrict__ e_cnt, const unsigned* __restrict__ csr,
                           const float* __restrict__ dinv, const float* __restrict__ bias,
                           const float* __restrict__ W, __hip_bfloat16* __restrict__ out_bf,
                           float* __restrict__ out_f, int n, int fuse) {
    __shared__ float sW[1024];
    if (fuse) {
        for (int i = threadIdx.x; i < 1024; i += 256) sW[i] = W[i];
        __syncthreads();
    }
    int t = blockIdx.x * 256 + threadIdx.x;
    int d = t >> 6;
    int lane = threadIdx.x & 63;
    int f = lane & 31, half = lane >> 5;
    if (d >= n) return;
    int e0 = e_start[d];
    int e1 = e0 + e_cnt[d];
    float a0 = 0.f, a1 = 0.f;
    int j = e0 + half;
    for (; j + 2 < e1; j += 4) {
        int s0 = (int)csr[j];
        int s1 = (int)csr[j + 2];
        a0 += __bfloat162float(u[(size_t)s0 * 32 + f]);
        a1 += __bfloat162float(u[(size_t)s1 * 32 + f]);
    }
    if (j < e1) a0 += __bfloat162float(u[(size_t)csr[j] * 32 + f]);
    float acc = a0 + a1;
    acc += __shfl_xor(acc, 32, 64);            // both halves now hold full sum
    float dv = dinv[d];
    float self = __bfloat162float(u[(size_t)d * 32 + f]);
    float v = fmaxf(dv * (acc + self) + bias[f], 0.f);  // replicated
    if (fuse) {
        float p = 0.f;
        int k0 = half << 4;                    // split-k: half 0 -> k=0..15, half 1 -> 16..31
#pragma unroll
        for (int k = 0; k < 16; k++) p += __shfl(v, k0 + k, 64) * sW[(k0 + k) * 32 + f];
        p += __shfl_xor(p, 32, 64);
        if (half == 0) out_bf[(size_t)d * 32 + f] = __float2bfloat16(dv * p);
    } else {
        if (half == 0) out_f[(size_t)d * 32 + f] = v;
    }
}

// ---------------- heads ----------------

__global__ void theta_kernel(const float* __restrict__ h, const float* __restrict__ Wt1,
                             const float* __restrict__ bt1, const float* __restrict__ Wt2,
                             const float* __restrict__ bt2, float* __restrict__ theta, int n) {
    __shared__ float sW[1024];
    __shared__ float sb[32];
    __shared__ float sw2[32];
    for (int i = threadIdx.x; i < 1024; i += 256) sW[i] = Wt1[i];
    if (threadIdx.x < 32) { sb[threadIdx.x] = bt1[threadIdx.x]; sw2[threadIdx.x] = Wt2[threadIdx.x]; }
    __syncthreads();
    int t = blockIdx.x * 256 + threadIdx.x;
    int node = t >> 5;
    int lane = threadIdx.x & 63;
    int f = lane & 31, base = lane & 32;
    if (node >= n) return;
    float hv = h[node * 32 + f];
    float a = sb[f];
#pragma unroll
    for (int k = 0; k < 32; k++) a += __shfl(hv, base | k, 64) * sW[k * 32 + f];
    a = fmaxf(a, 0.f) * sw2[f];
    a += __shfl_xor(a, 1, 64);
    a += __shfl_xor(a, 2, 64);
    a += __shfl_xor(a, 4, 64);
    a += __shfl_xor(a, 8, 64);
    a += __shfl_xor(a, 16, 64);
    if (f == 0) {
        float s = a + bt2[0];
        theta[node] = PI_F / (1.f + __expf(-s));
    }
}

__global__ void pool_kernel(const float* __restrict__ h, const int* __restrict__ batch,
                            float* __restrict__ gsum, float* __restrict__ gcnt, int n) {
    int f = threadIdx.x & 31;
    int sub = threadIdx.x >> 5;
    int start = blockIdx.x * 1024 + sub * 128;
    int end = min(start + 128, n);
    if (start >= end) return;
    int curg = batch[start];
    float acc = 0.f;
    int cnt = 0;
    for (int i = start; i < end; i++) {
        int g = batch[i];
        if (g != curg) {
            atomicAdd(&gsum[curg * 32 + f], acc);
            if (f == 0) atomicAdd(&gcnt[curg], (float)cnt);
            acc = 0.f; cnt = 0; curg = g;
        }
        acc += h[i * 32 + f];
        cnt++;
    }
    atomicAdd(&gsum[curg * 32 + f], acc);
    if (f == 0) atomicAdd(&gcnt[curg], (float)cnt);
}

__global__ void bg_kernel(const float* __restrict__ gsum, const float* __restrict__ gcnt,
                          const float* __restrict__ Wg1, const float* __restrict__ bg1,
                          const float* __restrict__ Wg2, const float* __restrict__ bg2,
                          float* __restrict__ out, int G) {
    __shared__ float sW[1024];
    for (int i = threadIdx.x; i < 1024; i += 256) sW[i] = Wg1[i];
    __syncthreads();
    int t = blockIdx.x * 256 + threadIdx.x;
    int g = t >> 5;
    int lane = threadIdx.x & 63;
    int f = lane & 31, base = lane & 32;
    if (g >= G) return;
    float cnt = fmaxf(gcnt[g], 1.f);
    float hv = gsum[g * 32 + f] / cnt;
    float a = bg1[f];
#pragma unroll
    for (int k = 0; k < 32; k++) a += __shfl(hv, base | k, 64) * sW[k * 32 + f];
    a = fmaxf(a, 0.f);
    float p0 = a * Wg2[f * 2 + 0];
    float p1 = a * Wg2[f * 2 + 1];
    for (int m = 1; m < 32; m <<= 1) {
        p0 += __shfl_xor(p0, m, 64);
        p1 += __shfl_xor(p1, m, 64);
    }
    if (f == 0) {
        out[g * 2 + 0] = 2.f * PI_F / (1.f + __expf(-(p0 + bg2[0])));
        out[g * 2 + 1] = 2.f * PI_F / (1.f + __expf(-(p1 + bg2[1])));
    }
}

// ---------------- launch ----------------

extern "C" void kernel_launch(void* const* d_in, const int* in_sizes, int n_in,
                              void* d_out, int out_size, void* d_ws, size_t ws_size,
                              hipStream_t stream) {
    const float* x   = (const float*)d_in[0];
    const int*   ei  = (const int*)d_in[1];
    const int* batch = (const int*)d_in[2];
    const float* W1  = (const float*)d_in[3];
    const float* b1  = (const float*)d_in[4];
    const float* W2  = (const float*)d_in[5];
    const float* b2  = (const float*)d_in[6];
    const float* W3  = (const float*)d_in[7];
    const float* b3  = (const float*)d_in[8];
    const float* Wt1 = (const float*)d_in[9];
    const float* bt1 = (const float*)d_in[10];
    const float* Wt2 = (const float*)d_in[11];
    const float* bt2 = (const float*)d_in[12];
    const float* Wg1 = (const float*)d_in[13];
    const float* bg1 = (const float*)d_in[14];
    const float* Wg2 = (const float*)d_in[15];
    const float* bg2 = (const float*)d_in[16];

    const int N = in_sizes[0];
    const int E = in_sizes[1] / 2;
    const int G = 128;
    const int* src = ei;
    const int* dst = ei + E;
    float* theta_out = (float*)d_out;
    float* bg_out = (float*)d_out + N;

    const int NBUCK = (N + 63) / 64;
    const int CHUNK = (E + NBLK - 1) / NBLK;

    char* w = (char*)d_ws;
    auto alloc = [&](size_t bytes) -> char* { char* p = w; w += align256(bytes); return p; };
    int*      C        = (int*)alloc((size_t)NBLK * NBUCK * 4);
    int*      colsum   = (int*)alloc((size_t)NBUCK * 4);
    int*      bbase    = (int*)alloc((size_t)(NBUCK + 1) * 4);
    unsigned* bkt_data = (unsigned*)alloc((size_t)E * 4);
    unsigned* csr      = (unsigned*)alloc((size_t)E * 4);
    int*      e_start  = (int*)alloc((size_t)N * 4);
    int*      e_cnt    = (int*)alloc((size_t)N * 4);
    float*    dinv     = (float*)alloc((size_t)N * 4);
    float*    xd       = (float*)alloc((size_t)N * 4);
    __hip_bfloat16* u2 = (__hip_bfloat16*)alloc((size_t)N * 32 * 2);
    __hip_bfloat16* u3 = (__hip_bfloat16*)alloc((size_t)N * 32 * 2);
    float*    hbuf     = (float*)alloc((size_t)N * 32 * 4);
    float*    gsum     = (float*)alloc((size_t)G * 32 * 4);
    float*    gcnt     = (float*)alloc((size_t)G * 4);

    hipMemsetAsync(gsum, 0, (size_t)G * 32 * 4, stream);
    hipMemsetAsync(gcnt, 0, (size_t)G * 4, stream);

    size_t ldsB = (size_t)NBUCK * 4;
    count_kernel<<<NBLK, 256, ldsB, stream>>>(dst, C, E, CHUNK, NBUCK);
    scan_blocks_kernel<<<NBUCK, 256, 0, stream>>>(C, colsum, NBUCK);
    scan_totals_kernel<<<1, 256, 0, stream>>>(colsum, bbase, NBUCK, E);
    scatter_kernel<<<NBLK, 256, ldsB, stream>>>(src, dst, C, bbase, bkt_data, E, CHUNK, NBUCK);
    csr_build_kernel<<<NBUCK, 256, 0, stream>>>(bkt_data, bbase, x, csr, e_start, e_cnt, dinv, xd, N);

    unsigned gridNF = (unsigned)(((size_t)N * 32 + 255) / 256);  // 32 lanes/node
    unsigned gridNW = (unsigned)(((size_t)N * 64 + 255) / 256);  // 64 lanes/node

    // layer 1 (rank-1 collapse) -> fused W2 -> u2 (bf16)
    agg1_kernel<<<gridNW, 256, 0, stream>>>(xd, e_start, e_cnt, csr, dinv, W1, b1, W2, u2, N);
    // layer 2 -> fused W3 -> u3 (bf16)
    agg_kernel<<<gridNW, 256, 0, stream>>>(u2, e_start, e_cnt, csr, dinv, b2, W3, u3, (float*)nullptr, N, 1);
    // layer 3 -> h (fp32)
    agg_kernel<<<gridNW, 256, 0, stream>>>(u3, e_start, e_cnt, csr, dinv, b3, (const float*)nullptr,
                                           (__hip_bfloat16*)nullptr, hbuf, N, 0);

    // heads
    theta_kernel<<<gridNF, 256, 0, stream>>>(hbuf, Wt1, bt1, Wt2, bt2, theta_out, N);
    pool_kernel<<<(N + 1023) / 1024, 256, 0, stream>>>(hbuf, batch, gsum, gcnt, N);
    bg_kernel<<<(G * 32 + 255) / 256, 256, 0, stream>>>(gsum, gcnt, Wg1, bg1, Wg2, bg2, bg_out, G);
}